// Round 11
// baseline (163.178 us; speedup 1.0000x reference)
//
#include <hip/hip_runtime.h>

#define H    128
#define P    32            // points per block
#define NT   512           // 8 waves: wave = jpair*2 + phalf
#define WSTR 40            // staged-W row stride in halves (32 k + 8 pad)

typedef _Float16 v8h __attribute__((ext_vector_type(8)));
typedef __fp16   h2  __attribute__((ext_vector_type(2)));   // cvt_pkrtz return type
typedef float    v4f __attribute__((ext_vector_type(4)));

union PK4 { h2 h[4]; uint4 u; };       // 8 f16 = 16 B

// State plane layout: [pl][p][k], 128 f16 per row, XOR-octet swizzle; returns
// f16 index of octet o of row p (row accesses b128-able, scatter ~4-way).
__device__ __forceinline__ int soct(int pl, int p, int o) {
    return ((pl * P + p) * 16 + (o ^ (p & 15))) << 3;
}

__device__ __forceinline__ void tanh_d2(float z, float& a, float& g1, float& g2) {
    const float e = __expf(2.f * z);
    a  = 1.f - 2.f / (e + 1.f);
    g1 = 1.f - a * a;
    g2 = -2.f * a * g1;
}

// Second-order forward-mode Hessian via f16 MFMA, z orientation (A = state,
// B = W^T). SINGLE DISPATCH: the f32->f16 W transpose is fused into staging
// (R4-R10 ran a separate prepass kernel; the 2nd dispatch cost a constant
// ~50us of graph serialization — bench-kernel gap 48-52us in every round,
// vs ~0 in single-kernel R3). Staging: thread (j,kg) gathers 8 rows of W at
// col j (coalesced b32, L2-resident), pkrtz, one b128 LDS write (all-32-bank
// spread = 8-phase floor for 16B/lane).
__global__ __launch_bounds__(NT, 4)
void pinn_hess_mfma(const float* __restrict__ X,
                    const float* __restrict__ W0, const float* __restrict__ b0,
                    const float* __restrict__ W1, const float* __restrict__ b1,
                    const float* __restrict__ W2, const float* __restrict__ b2,
                    const float* __restrict__ W3,
                    float* __restrict__ out, int N)
{
    __shared__ _Float16 sS[6 * P * H];        // 49152 B, swizzled state planes
    __shared__ _Float16 sW[2][H * WSTR];      // 2 x 10240 B, W-chunk double buffer

    const int tid   = threadIdx.x;
    const int wave  = tid >> 6;               // 0..7
    const int phalf = wave & 1;               // p-half: rows phalf*16..+16
    const int jpair = wave >> 1;              // j-tile pair: cols jpair*32..+32
    const int lane  = tid & 63;
    const int quad  = lane >> 4;
    const int l15   = lane & 15;
    const int pbase = blockIdx.x * P;

    // ---------------- layer 0 (input dim 2, analytic); 512 tasks = 1/thread --
    {
        const int p = tid >> 4, o = tid & 15;
        const float x = X[2 * (pbase + p)];
        const float y = X[2 * (pbase + p) + 1];
        float wxv[8], wyv[8], bv[8];
        *(float4*)&wxv[0] = *(const float4*)&W0[o * 8];
        *(float4*)&wxv[4] = *(const float4*)&W0[o * 8 + 4];
        *(float4*)&wyv[0] = *(const float4*)&W0[H + o * 8];
        *(float4*)&wyv[4] = *(const float4*)&W0[H + o * 8 + 4];
        *(float4*)&bv[0]  = *(const float4*)&b0[o * 8];
        *(float4*)&bv[4]  = *(const float4*)&b0[o * 8 + 4];
        float r[6][8];
        #pragma unroll
        for (int u = 0; u < 8; ++u) {
            float a, g1, g2;
            tanh_d2(fmaf(x, wxv[u], fmaf(y, wyv[u], bv[u])), a, g1, g2);
            r[0][u] = a;
            r[1][u] = g1 * wxv[u];
            r[2][u] = g1 * wyv[u];
            r[3][u] = g2 * wxv[u] * wxv[u];
            r[4][u] = g2 * wxv[u] * wyv[u];
            r[5][u] = g2 * wyv[u] * wyv[u];
        }
        #pragma unroll
        for (int pl = 0; pl < 6; ++pl) {
            PK4 q;
            #pragma unroll
            for (int h = 0; h < 4; ++h)
                q.h[h] = __builtin_amdgcn_cvt_pkrtz(r[pl][2*h], r[pl][2*h+1]);
            *(uint4*)&sS[soct(pl, p, o)] = q.u;
        }
    }

    // ---------------- hidden layers ----------------
    for (int layer = 0; layer < 2; ++layer) {
        const float* __restrict__ Wf = layer ? W2 : W1;

        // fused transpose+cvt staging of one 32-k chunk: sWt[j][k] = f16(W[k][j])
        auto stage = [&](int kc, int buf) {
            const int j  = tid & 127;          // output row (consecutive lanes -> coalesced)
            const int kg = tid >> 7;           // k-octet group 0..3
            const float* src = Wf + (kc * 32 + kg * 8) * H + j;
            float v[8];
            #pragma unroll
            for (int i = 0; i < 8; ++i) v[i] = src[i * H];
            PK4 q;
            #pragma unroll
            for (int h = 0; h < 4; ++h)
                q.h[h] = __builtin_amdgcn_cvt_pkrtz(v[2*h], v[2*h+1]);
            *(uint4*)&sW[buf][j * WSTR + kg * 8] = q.u;
        };

        stage(0, 0);        // sW[0] free since prev layer's kc2 barrier
        __syncthreads();    // chunk0 + state writes (L0 / prev combine) visible

        v4f C[6][2];
        #pragma unroll
        for (int pl = 0; pl < 6; ++pl) { C[pl][0] = (v4f){0,0,0,0}; C[pl][1] = (v4f){0,0,0,0}; }

        for (int kc = 0; kc < 4; ++kc) {
            const int buf = kc & 1;
            if (kc < 3) stage(kc + 1, buf ^ 1);
            // B-frags: rows j = jpair*32 + nt*16 + l15, k-octet quad of chunk
            const v8h B0 = *(const v8h*)&sW[buf][(jpair * 32 + l15)      * WSTR + quad * 8];
            const v8h B1 = *(const v8h*)&sW[buf][(jpair * 32 + 16 + l15) * WSTR + quad * 8];
            #pragma unroll
            for (int pl = 0; pl < 6; ++pl) {
                // A-frag: state plane pl, row p = phalf*16 + l15, octet kc*4+quad
                const v8h A = *(const v8h*)&sS[soct(pl, phalf * 16 + l15, kc * 4 + quad)];
                C[pl][0] = __builtin_amdgcn_mfma_f32_16x16x32_f16(A, B0, C[pl][0], 0, 0, 0);
                C[pl][1] = __builtin_amdgcn_mfma_f32_16x16x32_f16(A, B1, C[pl][1], 0, 0, 0);
            }
            __syncthreads();   // kc<3: dbuf swap; kc==3: drain reads before scatter
        }

        if (layer == 0) {
            // in-register tanh chain rule; scatter new state (b16, ~4-way banks)
            #pragma unroll
            for (int nt = 0; nt < 2; ++nt) {
                const int j  = jpair * 32 + nt * 16 + l15;
                const int ob = j >> 3, wi = j & 7;
                const float bb = b1[j];
                #pragma unroll
                for (int r = 0; r < 4; ++r) {
                    const int p = phalf * 16 + quad * 4 + r;
                    float a, g1, g2;
                    tanh_d2(C[0][nt][r] + bb, a, g1, g2);
                    const float tx = C[1][nt][r], ty = C[2][nt][r];
                    sS[soct(0, p, ob) + wi] = (_Float16)a;
                    sS[soct(1, p, ob) + wi] = (_Float16)(g1 * tx);
                    sS[soct(2, p, ob) + wi] = (_Float16)(g1 * ty);
                    sS[soct(3, p, ob) + wi] = (_Float16)fmaf(g2 * tx, tx, g1 * C[3][nt][r]);
                    sS[soct(4, p, ob) + wi] = (_Float16)fmaf(g2 * tx, ty, g1 * C[4][nt][r]);
                    sS[soct(5, p, ob) + wi] = (_Float16)fmaf(g2 * ty, ty, g1 * C[5][nt][r]);
                }
            }
            // visibility: next layer's post-stage(0,0) barrier
        } else {
            // final combine + W3 dot in registers; reduce j over l15 then jpair
            float hxx[4] = {0,0,0,0}, hxy[4] = {0,0,0,0}, hyy[4] = {0,0,0,0};
            #pragma unroll
            for (int nt = 0; nt < 2; ++nt) {
                const int j = jpair * 32 + nt * 16 + l15;
                const float bb = b2[j];
                const float w3 = W3[j];
                #pragma unroll
                for (int r = 0; r < 4; ++r) {
                    float a, g1, g2;
                    tanh_d2(C[0][nt][r] + bb, a, g1, g2);
                    const float tx = C[1][nt][r], ty = C[2][nt][r];
                    hxx[r] = fmaf(w3, fmaf(g2 * tx, tx, g1 * C[3][nt][r]), hxx[r]);
                    hxy[r] = fmaf(w3, fmaf(g2 * tx, ty, g1 * C[4][nt][r]), hxy[r]);
                    hyy[r] = fmaf(w3, fmaf(g2 * ty, ty, g1 * C[5][nt][r]), hyy[r]);
                }
            }
            #pragma unroll
            for (int off = 8; off > 0; off >>= 1)
                #pragma unroll
                for (int r = 0; r < 4; ++r) {
                    hxx[r] += __shfl_down(hxx[r], off, 16);
                    hxy[r] += __shfl_down(hxy[r], off, 16);
                    hyy[r] += __shfl_down(hyy[r], off, 16);
                }
            // sW[0] free (last read at kc2); scratch partial[c][jpair][p]
            float* sRed = (float*)&sW[0][0];
            if (l15 == 0) {
                #pragma unroll
                for (int r = 0; r < 4; ++r) {
                    const int p = phalf * 16 + quad * 4 + r;
                    sRed[0 * 128 + jpair * 32 + p] = hxx[r];
                    sRed[1 * 128 + jpair * 32 + p] = hxy[r];
                    sRed[2 * 128 + jpair * 32 + p] = hyy[r];
                }
            }
            __syncthreads();
            if (tid < 96) {
                const int c = tid >> 5, p = tid & 31;
                float acc = 0.f;
                #pragma unroll
                for (int jp = 0; jp < 4; ++jp)
                    acc += sRed[c * 128 + jp * 32 + p];
                out[c * N + pbase + p] = acc;
            }
        }
    }
}

extern "C" void kernel_launch(void* const* d_in, const int* in_sizes, int n_in,
                              void* d_out, int out_size, void* d_ws, size_t ws_size,
                              hipStream_t stream) {
    const float* X  = (const float*)d_in[0];
    const float* W0 = (const float*)d_in[1];
    const float* b0 = (const float*)d_in[2];
    const float* W1 = (const float*)d_in[3];
    const float* b1 = (const float*)d_in[4];
    const float* W2 = (const float*)d_in[5];
    const float* b2 = (const float*)d_in[6];
    const float* W3 = (const float*)d_in[7];
    // d_in[8] = b3: constant offset, zero second derivative -> unused.

    const int N = in_sizes[0] / 2;               // 131072 = 4096 * P
    float* out = (float*)d_out;

    hipLaunchKernelGGL(pinn_hess_mfma, dim3(N / P), dim3(NT), 0, stream,
                       X, W0, b0, W1, b1, W2, b2, W3, out, N);
}